// Round 1
// baseline (12475.915 us; speedup 1.0000x reference)
//
#include <hip/hip_runtime.h>
#include <hip/hip_bf16.h>

#define BN 2
#define C0 64
#define HH 160
#define WW 160
#define HWn (HH*WW)          // 25600
#define PN (BN*HWn)          // 51200
#define DWCH 128
#define GN 4
#define KN 9
#define CG 32
#define OMC 108

__device__ __forceinline__ float ldin(const void* p, int i, int bf) {
  return bf ? __bfloat162float(((const __hip_bfloat16*)p)[i])
            : ((const float*)p)[i];
}
__device__ __forceinline__ void stout(void* p, long i, float v, int bf) {
  if (bf) ((__hip_bfloat16*)p)[i] = __float2bfloat16(v);
  else    ((float*)p)[i] = v;
}

// ---- dtype probe: ln1_g is all-ones. fp32 1.0 = 0x3F800000; bf16 (1.0,1.0) = 0x3F803F80
__global__ void k_flag(const void* g1, int* flag) {
  unsigned w = *(const unsigned*)g1;
  *flag = (w == 0x3F800000u) ? 0 : 1;
}

// ---- 1. LayerNorm(64) + pw1 (64->128), output NHWC
__global__ void k_ln_pw1(const void* x, const void* ln_g, const void* w, const void* bias,
                         float* __restrict__ h1, const int* flagp) {
  const int bf = *flagp;
  const int p = blockIdx.x, t = threadIdx.x;
  const int b = p / HWn, rem = p % HWn;
  __shared__ float xs[C0];
  __shared__ float red[128];
  float xv = 0.f;
  if (t < C0) xv = ldin(x, (b*C0 + t)*HWn + rem, bf);
  red[t] = (t < C0) ? xv : 0.f; __syncthreads();
  for (int s = 64; s > 0; s >>= 1) { if (t < s) red[t] += red[t+s]; __syncthreads(); }
  const float mean = red[0] / C0; __syncthreads();
  red[t] = (t < C0) ? (xv-mean)*(xv-mean) : 0.f; __syncthreads();
  for (int s = 64; s > 0; s >>= 1) { if (t < s) red[t] += red[t+s]; __syncthreads(); }
  const float rstd = rsqrtf(red[0] / C0 + 1e-5f); __syncthreads();
  if (t < C0) xs[t] = (xv - mean) * rstd * ldin(ln_g, t, bf);
  __syncthreads();
  float acc = ldin(bias, t, bf);
  #pragma unroll 8
  for (int c = 0; c < C0; ++c) acc += xs[c] * ldin(w, t*C0 + c, bf);
  h1[p*DWCH + t] = acc;
}

// ---- 2. v = h1 @ val_w.T + val_b
__global__ void k_val(const float* __restrict__ h1, const void* w, const void* bias,
                      float* __restrict__ v, const int* flagp) {
  const int bf = *flagp;
  const int p = blockIdx.x, t = threadIdx.x;
  __shared__ float xs[DWCH];
  xs[t] = h1[p*DWCH + t];
  __syncthreads();
  float acc = ldin(bias, t, bf);
  #pragma unroll 8
  for (int i = 0; i < DWCH; ++i) acc += xs[i] * ldin(w, t*DWCH + i, bf);
  v[p*DWCH + t] = acc;
}

// ---- 3. depthwise 3x3 (SAME) + om head (128->108): off/mask
__global__ void k_dwom(const float* __restrict__ h1, const void* dwc_w, const void* dwc_b,
                       const void* om_w, const void* om_b,
                       float* __restrict__ om, const int* flagp) {
  const int bf = *flagp;
  const int p = blockIdx.x, t = threadIdx.x;
  const int b = p / HWn, rem = p % HWn, h = rem / WW, w = rem % WW;
  __shared__ float dws[DWCH];
  float acc = ldin(dwc_b, t, bf);
  #pragma unroll
  for (int ky = 0; ky < 3; ++ky)
    #pragma unroll
    for (int kx = 0; kx < 3; ++kx) {
      const int hh = h + ky - 1, ww2 = w + kx - 1;
      if (hh >= 0 && hh < HH && ww2 >= 0 && ww2 < WW)
        acc += h1[((b*HWn + hh*WW + ww2)*DWCH) + t] * ldin(dwc_w, (ky*3+kx)*DWCH + t, bf);
    }
  dws[t] = acc;
  __syncthreads();
  if (t < OMC) {
    float o = ldin(om_b, t, bf);
    #pragma unroll 8
    for (int ch = 0; ch < DWCH; ++ch) o += dws[ch] * ldin(om_w, t*DWCH + ch, bf);
    om[p*OMC + t] = o;
  }
}

// ---- 4. deformable bilinear sampling + outp (128->128) + SimpleGate -> f (NHWC, 64ch)
__global__ void k_samp(const float* __restrict__ v, const float* __restrict__ om,
                       const void* outp_w, const void* outp_b,
                       float* __restrict__ f, const int* flagp) {
  const int bf = *flagp;
  const int p = blockIdx.x, t = threadIdx.x;
  const int b = p / HWn, rem = p % HWn, h = rem / WW, w = rem % WW;
  __shared__ float oml[OMC];
  __shared__ float samp[DWCH];
  __shared__ float ov[DWCH];
  if (t < OMC) oml[t] = om[p*OMC + t];
  __syncthreads();
  const int g = t >> 5, c = t & 31;
  const float* vb = v + (long)b*HWn*DWCH;
  float acc = 0.f;
  #pragma unroll
  for (int k = 0; k < KN; ++k) {
    const float offx = oml[(g*KN + k)*3 + 0];
    const float offy = oml[(g*KN + k)*3 + 1];
    const float m    = oml[(g*KN + k)*3 + 2];
    // px = (w+1.5) + kx + offx - 0.5, kx = k%3 - 1  ->  w + k%3 + offx   (padded coords, Wp=162)
    const float px = (float)(w + (k % 3)) + offx;
    const float py = (float)(h + (k / 3)) + offy;
    const float x0f = floorf(px), y0f = floorf(py);
    const float tx = px - x0f, ty = py - y0f;
    const int x0 = (int)x0f, y0 = (int)y0f;
    #pragma unroll
    for (int dy = 0; dy < 2; ++dy)
      #pragma unroll
      for (int dx = 0; dx < 2; ++dx) {
        const int xi = x0 + dx, yi = y0 + dy;
        if (xi >= 0 && xi < WW+2 && yi >= 0 && yi < HH+2) {
          const float wq = (dx ? tx : 1.f - tx) * (dy ? ty : 1.f - ty) * m;
          float val = 0.f;
          if (xi >= 1 && xi <= WW && yi >= 1 && yi <= HH)
            val = vb[((yi-1)*WW + (xi-1))*DWCH + (g*CG + c)];
          acc += wq * val;
        }
      }
  }
  samp[t] = acc;
  __syncthreads();
  float o = ldin(outp_b, t, bf);
  #pragma unroll 8
  for (int ch = 0; ch < DWCH; ++ch) o += samp[ch] * ldin(outp_w, t*DWCH + ch, bf);
  ov[t] = o;
  __syncthreads();
  if (t < C0) f[p*C0 + t] = ov[t] * ov[t + C0];
}

// ---- 5. spatial mean pool per (b, ch of 128)
__global__ void k_pool(const float* __restrict__ fL, const float* __restrict__ fR,
                       float* __restrict__ pooled) {
  const int b = blockIdx.x >> 7, ch = blockIdx.x & 127;
  const int t = threadIdx.x;
  const float* src = (ch < C0) ? fL : fR;
  const int cc = ch & (C0-1);
  float s = 0.f;
  for (int i = t; i < HWn; i += 256) s += src[(b*HWn + i)*C0 + cc];
  __shared__ float red[256];
  red[t] = s; __syncthreads();
  for (int k = 128; k > 0; k >>= 1) { if (t < k) red[t] += red[t+k]; __syncthreads(); }
  if (t == 0) pooled[b*DWCH + ch] = red[0] / (float)HWn;
}

// ---- 6. scale = sca_w @ pooled + sca_b
__global__ void k_scale(const float* __restrict__ pooled, const void* sca_w, const void* sca_b,
                        float* __restrict__ scale, const int* flagp) {
  const int bf = *flagp;
  const int t = threadIdx.x;  // 256
  const int b = t >> 7, o = t & 127;
  float acc = ldin(sca_b, o, bf);
  for (int ch = 0; ch < DWCH; ++ch) acc += pooled[b*DWCH + ch] * ldin(sca_w, o*DWCH + ch, bf);
  scale[b*DWCH + o] = acc;
}

// ---- 7. x*scale -> conv3 (128->64), y = x_in + x3*beta  (y stored NHWC)
__global__ void k_conv3(const float* __restrict__ fL, const float* __restrict__ fR,
                        const float* __restrict__ scale,
                        const void* c3_w, const void* c3_b, const void* beta,
                        const void* x_l, const void* x_r,
                        float* __restrict__ yL, float* __restrict__ yR, const int* flagp) {
  const int bf = *flagp;
  const int p = blockIdx.x, t = threadIdx.x;
  const int b = p / HWn, rem = p % HWn;
  __shared__ float xc[DWCH];
  __shared__ float x3s[C0];
  const float xv = (t < C0) ? fL[p*C0 + t] : fR[p*C0 + (t - C0)];
  xc[t] = xv * scale[b*DWCH + t];
  __syncthreads();
  if (t < C0) {
    float a = ldin(c3_b, t, bf);
    #pragma unroll 8
    for (int ch = 0; ch < DWCH; ++ch) a += xc[ch] * ldin(c3_w, t*DWCH + ch, bf);
    x3s[t] = a;
  }
  __syncthreads();
  const int c = t & (C0-1);
  const float yadd = x3s[c] * ldin(beta, c, bf);
  if (t < C0) yL[p*C0 + t] = ldin(x_l, (b*C0 + t)*HWn + rem, bf) + yadd;
  else        yR[p*C0 + c] = ldin(x_r, (b*C0 + c)*HWn + rem, bf) + yadd;
}

// ---- 8. LN(128) + conv4 (128->128) + SG + conv5 (64->64); out = y + z*gamma, NCHW
__global__ void k_final(const float* __restrict__ yL, const float* __restrict__ yR,
                        const void* n2_g, const void* c4_w, const void* c4_b,
                        const void* c5_w, const void* c5_b, const void* gamma,
                        void* dout, const int* flagp) {
  const int bf = *flagp;
  const int p = blockIdx.x, t = threadIdx.x;
  const int b = p / HWn, rem = p % HWn;
  __shared__ float red[DWCH];
  __shared__ float ns[DWCH];
  __shared__ float t4[DWCH];
  __shared__ float sgs[C0];
  __shared__ float zs[C0];
  const float yv = (t < C0) ? yL[p*C0 + t] : yR[p*C0 + (t - C0)];
  red[t] = yv; __syncthreads();
  for (int s = 64; s > 0; s >>= 1) { if (t < s) red[t] += red[t+s]; __syncthreads(); }
  const float mean = red[0] / DWCH; __syncthreads();
  red[t] = (yv-mean)*(yv-mean); __syncthreads();
  for (int s = 64; s > 0; s >>= 1) { if (t < s) red[t] += red[t+s]; __syncthreads(); }
  const float rstd = rsqrtf(red[0] / DWCH + 1e-5f); __syncthreads();
  ns[t] = (yv - mean) * rstd * ldin(n2_g, t, bf);
  __syncthreads();
  float a = ldin(c4_b, t, bf);
  #pragma unroll 8
  for (int ch = 0; ch < DWCH; ++ch) a += ns[ch] * ldin(c4_w, t*DWCH + ch, bf);
  t4[t] = a;
  __syncthreads();
  if (t < C0) sgs[t] = t4[t] * t4[t + C0];
  __syncthreads();
  if (t < C0) {
    float z = ldin(c5_b, t, bf);
    #pragma unroll 8
    for (int c2 = 0; c2 < C0; ++c2) z += sgs[c2] * ldin(c5_w, t*C0 + c2, bf);
    zs[t] = z * ldin(gamma, t, bf);
  }
  __syncthreads();
  const int c = t & (C0-1), side = t >> 6;
  const long oidx = (long)side*((long)BN*C0*HWn) + ((long)(b*C0 + c))*HWn + rem;
  stout(dout, oidx, yv + zs[c], bf);
}

extern "C" void kernel_launch(void* const* d_in, const int* in_sizes, int n_in,
                              void* d_out, int out_size, void* d_ws, size_t ws_size,
                              hipStream_t stream) {
  const void* x_l    = d_in[0];
  const void* x_r    = d_in[1];
  const void* ln1_g  = d_in[2];
  const void* pw1_w  = d_in[3];
  const void* pw1_b  = d_in[4];
  const void* val_w  = d_in[5];
  const void* val_b  = d_in[6];
  const void* dwc_w  = d_in[7];
  const void* dwc_b  = d_in[8];
  const void* om_w   = d_in[9];
  const void* om_b   = d_in[10];
  const void* outp_w = d_in[11];
  const void* outp_b = d_in[12];
  const void* sca_w  = d_in[13];
  const void* sca_b  = d_in[14];
  const void* conv3_w = d_in[15];
  const void* conv3_b = d_in[16];
  const void* norm2_g = d_in[17];
  const void* conv4_w = d_in[18];
  const void* conv4_b = d_in[19];
  const void* conv5_w = d_in[20];
  const void* conv5_b = d_in[21];
  const void* beta   = d_in[22];
  const void* gamma  = d_in[23];

  int* flag  = (int*)d_ws;
  float* wsf = (float*)((char*)d_ws + 64);
  const long S128 = (long)PN*DWCH, S108 = (long)PN*OMC, S64v = (long)PN*C0;
  float* h1 = wsf;
  float* vv = wsf + S128;
  float* om = wsf + 2*S128;
  float* fL = om + S108;
  float* fR = fL + S64v;
  float* pooled = fR + S64v;
  float* scale  = pooled + 256;
  float* yL = h1;            // h1 region reused after both sides done
  float* yR = h1 + S64v;

  hipLaunchKernelGGL(k_flag, dim3(1), dim3(1), 0, stream, ln1_g, flag);

  for (int s = 0; s < 2; ++s) {
    const void* x = s ? x_r : x_l;
    float* f = s ? fR : fL;
    hipLaunchKernelGGL(k_ln_pw1, dim3(PN), dim3(128), 0, stream, x, ln1_g, pw1_w, pw1_b, h1, flag);
    hipLaunchKernelGGL(k_val,    dim3(PN), dim3(128), 0, stream, h1, val_w, val_b, vv, flag);
    hipLaunchKernelGGL(k_dwom,   dim3(PN), dim3(128), 0, stream, h1, dwc_w, dwc_b, om_w, om_b, om, flag);
    hipLaunchKernelGGL(k_samp,   dim3(PN), dim3(128), 0, stream, vv, om, outp_w, outp_b, f, flag);
  }
  hipLaunchKernelGGL(k_pool,  dim3(256), dim3(256), 0, stream, fL, fR, pooled);
  hipLaunchKernelGGL(k_scale, dim3(1),   dim3(256), 0, stream, pooled, sca_w, sca_b, scale, flag);
  hipLaunchKernelGGL(k_conv3, dim3(PN),  dim3(128), 0, stream, fL, fR, scale, conv3_w, conv3_b, beta,
                     x_l, x_r, yL, yR, flag);
  hipLaunchKernelGGL(k_final, dim3(PN),  dim3(128), 0, stream, yL, yR, norm2_g, conv4_w, conv4_b,
                     conv5_w, conv5_b, gamma, d_out, flag);
}